// Round 9
// baseline (216.479 us; speedup 1.0000x reference)
//
#include <hip/hip_runtime.h>
#include <math.h>

#define FT_OUT 256
#define VFT 640
#define CAP 96        // per-row bucket capacity; Poisson(32) max ~56-60, 96 = +11 sigma
#define CPAD 16       // counter stride in ints (64 B)
#define SLICE 32      // outputs per XCD slice
#define NSLICE 8      // FT_OUT / SLICE == number of XCDs

typedef _Float16 half8_t __attribute__((ext_vector_type(8)));
typedef float    float8_t __attribute__((ext_vector_type(8)));

// ---------------- fill: 4 nnz x 2 sides per thread, 8 independent chains ----------------
__global__ __launch_bounds__(256) void fill_k(
    const int* __restrict__ stm, const int* __restrict__ nstm,
    const float* __restrict__ vals, int nnz,
    int* __restrict__ cnt_s, int* __restrict__ cnt_n,
    int2* __restrict__ slot_s, int2* __restrict__ slot_n)
{
    int k0 = ((int)blockIdx.x * 256 + threadIdx.x) * 4;
    if (k0 >= nnz) return;
    if (k0 + 4 <= nnz) {
        const int4 rs = *(const int4*)(stm + k0);
        const int4 cs = *(const int4*)(stm + nnz + k0);
        const int4 rn = *(const int4*)(nstm + k0);
        const int4 cn = *(const int4*)(nstm + nnz + k0);
        const int4 vv = *(const int4*)(vals + k0);  // raw bits
        int rsa[4] = {rs.x, rs.y, rs.z, rs.w}, csa[4] = {cs.x, cs.y, cs.z, cs.w};
        int rna[4] = {rn.x, rn.y, rn.z, rn.w}, cna[4] = {cn.x, cn.y, cn.z, cn.w};
        int va[4] = {vv.x, vv.y, vv.z, vv.w};
        int ps[4], pn[4];
#pragma unroll
        for (int e = 0; e < 4; e++) ps[e] = atomicAdd(&cnt_s[rsa[e] * CPAD], 1);
#pragma unroll
        for (int e = 0; e < 4; e++) pn[e] = atomicAdd(&cnt_n[rna[e] * CPAD], 1);
#pragma unroll
        for (int e = 0; e < 4; e++)
            if (ps[e] < CAP) slot_s[(size_t)rsa[e] * CAP + ps[e]] = make_int2(csa[e], va[e]);
#pragma unroll
        for (int e = 0; e < 4; e++)
            if (pn[e] < CAP) slot_n[(size_t)rna[e] * CAP + pn[e]] = make_int2(cna[e], va[e]);
    } else {
        for (int k = k0; k < nnz; k++) {
            int vb = __float_as_int(vals[k]);
            int r = stm[k], c = stm[nnz + k];
            int pos = atomicAdd(&cnt_s[r * CPAD], 1);
            if (pos < CAP) slot_s[(size_t)r * CAP + pos] = make_int2(c, vb);
            r = nstm[k]; c = nstm[nnz + k];
            pos = atomicAdd(&cnt_n[r * CPAD], 1);
            if (pos < CAP) slot_n[(size_t)r * CAP + pos] = make_int2(c, vb);
        }
    }
}

// ---- build: W2s[slice][col][32] = (half)(ft_w[o][col] + fft_w[o][col%640]) ----
// index(col, o) = ((o>>5)*ft_in + col)*32 + (o&31)
__global__ __launch_bounds__(256) void build_k(
    const float* __restrict__ ft_w, const float* __restrict__ fft_w,
    _Float16* __restrict__ W2s, int ft_in)
{
    __shared__ float tile[64][65];  // [out][col], sum of ft+fft
    int bx = (int)blockIdx.x;
    int cb = (bx >> 2) * 64;     // 640 col tiles
    int ob = (bx & 3) * 64;      // 4 out tiles
    int fvb = cb % VFT;          // 640 % 64 == 0 -> contiguous 64-col window
    int tc4 = threadIdx.x & 15, tr = threadIdx.x >> 4;
#pragma unroll
    for (int i = 0; i < 4; i++) {
        int o = i * 16 + tr;
        const float4 f = *(const float4*)(ft_w + (size_t)(ob + o) * ft_in + cb + tc4 * 4);
        const float4 g = *(const float4*)(fft_w + (size_t)(ob + o) * VFT + fvb + tc4 * 4);
        tile[o][tc4 * 4 + 0] = f.x + g.x; tile[o][tc4 * 4 + 1] = f.y + g.y;
        tile[o][tc4 * 4 + 2] = f.z + g.z; tile[o][tc4 * 4 + 3] = f.w + g.w;
    }
    __syncthreads();
    int g = threadIdx.x & 7, cl = threadIdx.x >> 3;
#pragma unroll
    for (int i = 0; i < 2; i++) {
        int c = i * 32 + cl, col = cb + c;
        int obase = ob + g * 8;
        int slice = obase >> 5, sub = obase & 31;  // sub in {0,8,16,24}
        half8_t h;
#pragma unroll
        for (int jj = 0; jj < 8; jj++) h[jj] = (_Float16)tile[g * 8 + jj][c];
        *(half8_t*)(W2s + (((size_t)(slice * ft_in + col)) << 5) + sub) = h;
    }
}

// ---- XCD-sliced gather, 16-entry-parallel: blockIdx%8 = slice (2.5 MB, L2-resident) ----
// Wave = (row, slice), sides sequential. Lane: g=lane>>2 entry group (16 parallel
// entries), q=lane&3 out-octet; each lane loads half8 (16B) -> 1024 B/wave-load
// covering 16 entries (same instrs/byte as flat scheme, but XCD-local reads).
__global__ __launch_bounds__(256) void gather_k(
    const _Float16* __restrict__ W2s,
    const int* __restrict__ cnt_s, const int2* __restrict__ slot_s,
    const int* __restrict__ cnt_n, const int2* __restrict__ slot_n,
    const float* __restrict__ ft_b, const float* __restrict__ fft_b,
    const float* __restrict__ out_w, float* __restrict__ racc, int ft_in)
{
    int slice = blockIdx.x & 7;
    int wid   = threadIdx.x >> 6;
    int lane  = threadIdx.x & 63;
    int row   = (blockIdx.x >> 3) * 4 + wid;
    int g     = lane >> 2;   // 0..15: parallel entry index
    int q     = lane & 3;    // out octet within slice
    const _Float16* Wt = W2s + (((size_t)slice * ft_in) << 5) + q * 8;
    int og = slice * SLICE + q * 8;

    const float4* fb4 = (const float4*)(ft_b + og);
    const float4* gb4 = (const float4*)(fft_b + og);
    float4 fb0 = fb4[0], fb1 = fb4[1], gb0 = gb4[0], gb1 = gb4[1];
    float bias[8] = {fb0.x + gb0.x, fb0.y + gb0.y, fb0.z + gb0.z, fb0.w + gb0.w,
                     fb1.x + gb1.x, fb1.y + gb1.y, fb1.z + gb1.z, fb1.w + gb1.w};

    float wsum = 0.f;
#pragma unroll
    for (int side = 0; side < 2; side++) {
        const int*  cnt  = side ? cnt_n : cnt_s;
        const int2* slot = (side ? slot_n : slot_s) + (size_t)row * CAP;
        int n = min(cnt[row * CPAD], CAP);

        float8_t acc;
#pragma unroll
        for (int k = 0; k < 8; k++) acc[k] = 0.f;

#define CHUNK(jbase, PRED)                                                          \
    {                                                                               \
        int e = (jbase) + g;                                                        \
        unsigned long long pe = __builtin_nontemporal_load(                         \
            (const unsigned long long*)(slot + ((PRED) ? ((e < n) ? e : 0) : e)));  \
        int   c_ = (int)(pe & 0xffffffffu);                                         \
        float v_ = __int_as_float((int)(pe >> 32));                                 \
        if (PRED) v_ = (e < n) ? v_ : 0.f;                                          \
        const half8_t w_ = *(const half8_t*)(Wt + ((size_t)c_ << 5));               \
        _Pragma("unroll")                                                           \
        for (int k = 0; k < 8; k++) acc[k] += v_ * (float)w_[k];                    \
    }

        int j = 0;
        for (; j + 32 <= n; j += 32) { CHUNK(j, 0) CHUNK(j + 16, 0) }
        for (; j < n; j += 16) { CHUNK(j, 1) }
#undef CHUNK

        // reduce over the 16 entry groups (lanes sharing q)
#pragma unroll
        for (int m = 4; m <= 32; m <<= 1) {
#pragma unroll
            for (int k = 0; k < 8; k++) acc[k] += __shfl_xor(acc[k], m, 64);
        }
        // bias (once, post-reduce) + clip + partial dot
        const float4* ow4 = (const float4*)(out_w + side * FT_OUT + og);
        float4 ow0 = ow4[0], ow1 = ow4[1];
        float owf[8] = {ow0.x, ow0.y, ow0.z, ow0.w, ow1.x, ow1.y, ow1.z, ow1.w};
#pragma unroll
        for (int k = 0; k < 8; k++) {
            float h = fminf(fmaxf(acc[k] + bias[k], 0.f), 1.f);
            wsum += h * owf[k];
        }
    }
    // reduce over the 4 out-octets (q); lanes duplicate across g, take lane 0
    wsum += __shfl_xor(wsum, 1, 64);
    wsum += __shfl_xor(wsum, 2, 64);
    if (lane == 0) atomicAdd(&racc[row], wsum);
}

// ---- epilogue: sigmoid over per-row sums ----
__global__ void sigmoid_k(const float* __restrict__ racc, const float* __restrict__ out_b,
                          float* __restrict__ out, int B) {
    int i = blockIdx.x * 256 + threadIdx.x;
    if (i < B) out[i] = 1.f / (1.f + __expf(-(racc[i] + out_b[0])));
}

extern "C" void kernel_launch(void* const* d_in, const int* in_sizes, int n_in,
                              void* d_out, int out_size, void* d_ws, size_t ws_size,
                              hipStream_t stream) {
    const int*   stm    = (const int*)d_in[0];   // [2, NNZ]: rows then cols
    const int*   nstm   = (const int*)d_in[1];
    const float* values = (const float*)d_in[2];
    const float* ft_w   = (const float*)d_in[4];
    const float* ft_b   = (const float*)d_in[5];
    const float* fft_w  = (const float*)d_in[6];
    const float* fft_b  = (const float*)d_in[7];
    const float* out_w  = (const float*)d_in[8];
    const float* out_b  = (const float*)d_in[9];
    float* out = (float*)d_out;

    int B = out_size;                 // 8192
    int nnz = in_sizes[0] / 2;        // 262144
    int ft_in = in_sizes[4] / FT_OUT; // 40960

    // workspace layout (16B-aligned pieces); cnt_s/cnt_n/racc contiguous for one memset
    _Float16* W2s  = (_Float16*)d_ws;                          // ft_in*256 halfs (20 MB)
    int2*  slot_s  = (int2*)(W2s + (size_t)ft_in * FT_OUT);    // B*CAP entries (6 MB)
    int2*  slot_n  = slot_s + (size_t)B * CAP;                 // 6 MB
    int*   cnt_s   = (int*)(slot_n + (size_t)B * CAP);         // B*CPAD
    int*   cnt_n   = cnt_s + (size_t)B * CPAD;                 // B*CPAD
    float* racc    = (float*)(cnt_n + (size_t)B * CPAD);       // B

    int nfill  = (nnz / 4 + 255) / 256;                        // 256
    int nbuild = (ft_in / 64) * (FT_OUT / 64);                 // 2560

    hipMemsetAsync(cnt_s, 0, (2 * (size_t)B * CPAD + B) * sizeof(int), stream);
    fill_k<<<nfill, 256, 0, stream>>>(stm, nstm, values, nnz,
                                      cnt_s, cnt_n, slot_s, slot_n);
    build_k<<<nbuild, 256, 0, stream>>>(ft_w, fft_w, W2s, ft_in);
    gather_k<<<(B / 4) * NSLICE, 256, 0, stream>>>(W2s, cnt_s, slot_s, cnt_n, slot_n,
                                                   ft_b, fft_b, out_w, racc, ft_in);
    sigmoid_k<<<(B + 255) / 256, 256, 0, stream>>>(racc, out_b, out, B);
}